// Round 1
// baseline (2093.593 us; speedup 1.0000x reference)
//
#include <hip/hip_runtime.h>

// Problem constants
#define B_    8
#define T_    1024
#define D_    1024
#define H_    16
#define HS_   64
#define E_    8
#define DFF   4096
#define NTOK  8192    // B*T
#define NROW  16384   // NTOK * top-2

typedef unsigned short u16;
typedef unsigned int   u32;
typedef __attribute__((ext_vector_type(8))) short bf8;   // 8 bf16 in 4 VGPRs
typedef __attribute__((ext_vector_type(4))) float f4;    // MFMA accumulator

__device__ __forceinline__ u16 f2bf(float f) {
  u32 u = __float_as_uint(f);
  u32 r = (u + 0x7FFFu + ((u >> 16) & 1u)) >> 16;  // RNE
  return (u16)r;
}
__device__ __forceinline__ float bf2f(u16 h) {
  return __uint_as_float(((u32)h) << 16);
}

__device__ __forceinline__ f4 mfma16(bf8 a, bf8 b, f4 c) {
  return __builtin_amdgcn_mfma_f32_16x16x32_bf16(a, b, c, 0, 0, 0);
}

// ---------------------------------------------------------------- converts
__global__ __launch_bounds__(256) void cvt_x_kernel(const float* __restrict__ x,
                                                    u16* __restrict__ xbf) {
  int i = blockIdx.x * 256 + threadIdx.x;  // float4 index
  float4 v = ((const float4*)x)[i];
  ushort4 o;
  o.x = f2bf(v.x); o.y = f2bf(v.y); o.z = f2bf(v.z); o.w = f2bf(v.w);
  ((ushort4*)xbf)[i] = o;
}

// src fp32 [R x C] -> dst bf16 [C x R], batched along z
__global__ __launch_bounds__(256) void transpose_cvt_kernel(
    const float* __restrict__ src, u16* __restrict__ dst,
    int R, int C, size_t sStride, size_t dStride) {
  __shared__ float t[32][33];
  src += (size_t)blockIdx.z * sStride;
  dst += (size_t)blockIdx.z * dStride;
  int r0 = blockIdx.x * 32, c0 = blockIdx.y * 32;
  int tx = threadIdx.x & 31, ty = threadIdx.x >> 5;  // ty 0..7
#pragma unroll
  for (int i = 0; i < 32; i += 8)
    t[ty + i][tx] = src[(size_t)(r0 + ty + i) * C + (c0 + tx)];
  __syncthreads();
#pragma unroll
  for (int i = 0; i < 32; i += 8)
    dst[(size_t)(c0 + ty + i) * R + (r0 + tx)] = f2bf(t[tx][ty + i]);
}

// ---------------------------------------------------------------- gating
// exact fp32 gating so top-2 selection matches the reference
__global__ __launch_bounds__(256) void gating_kernel(
    const float* __restrict__ x, const float* __restrict__ Wg,
    int* __restrict__ sel, float* __restrict__ wgt) {
  int wave = threadIdx.x >> 6, lane = threadIdx.x & 63;
  int t = blockIdx.x * 4 + wave;
  int e = lane & 7, grp = lane >> 3;
  const float* xr = x + (size_t)t * D_;
  float acc = 0.f;
  for (int i = 0; i < 128; ++i) {
    int d = grp + i * 8;
    acc += xr[d] * Wg[d * 8 + e];   // Wg index = 64*i + lane : coalesced
  }
  acc += __shfl_xor(acc, 8);
  acc += __shfl_xor(acc, 16);
  acc += __shfl_xor(acc, 32);
  float lg[8];
#pragma unroll
  for (int j = 0; j < 8; ++j) lg[j] = __shfl(acc, j);
  int s0 = 0; float v0 = lg[0];
#pragma unroll
  for (int j = 1; j < 8; ++j) if (lg[j] > v0) { v0 = lg[j]; s0 = j; }
  int s1 = -1; float v1 = -3.4e38f;
#pragma unroll
  for (int j = 0; j < 8; ++j) if (j != s0 && lg[j] > v1) { v1 = lg[j]; s1 = j; }
  if (lane == 0) {
    float dd = __expf(v1 - v0);
    float w0 = 1.f / (1.f + dd);
    sel[2 * t]     = s0; sel[2 * t + 1] = s1;
    wgt[2 * t]     = w0; wgt[2 * t + 1] = dd * w0;
  }
}

// counts + exclusive offsets -> meta[0..7]=counts, meta[8..15]=offsets
__global__ __launch_bounds__(256) void offsets_kernel(const int* __restrict__ sel,
                                                      int* __restrict__ meta) {
  __shared__ int hist[E_];
  int tid = threadIdx.x;
  if (tid < E_) hist[tid] = 0;
  __syncthreads();
  for (int i = tid; i < NROW; i += 256) atomicAdd(&hist[sel[i]], 1);
  __syncthreads();
  if (tid == 0) {
    int s = 0;
    for (int e = 0; e < E_; ++e) { int c = hist[e]; meta[e] = c; meta[8 + e] = s; s += c; }
  }
}

// deterministic per-expert stable assignment via block scan
__global__ __launch_bounds__(256) void assign_kernel(
    const int* __restrict__ sel, const float* __restrict__ wgt,
    const int* __restrict__ meta, int* __restrict__ gidx,
    float* __restrict__ gw, int* __restrict__ rowmap) {
  int e = blockIdx.x, tid = threadIdx.x;
  __shared__ int buf[256];
  __shared__ int carry;
  if (tid == 0) carry = meta[8 + e];
  __syncthreads();
  for (int base = 0; base < NROW; base += 256) {
    int idx = base + tid;
    int f = (sel[idx] == e) ? 1 : 0;
    int cb = carry;
    buf[tid] = f;
    __syncthreads();
    for (int off = 1; off < 256; off <<= 1) {
      int v = (tid >= off) ? buf[tid - off] : 0;
      __syncthreads();
      buf[tid] += v;
      __syncthreads();
    }
    int incl = buf[tid];
    int total = buf[255];
    if (f) {
      int pos = cb + incl - 1;
      gidx[pos] = idx >> 1;
      gw[pos] = wgt[idx];
      rowmap[idx] = pos;
    }
    __syncthreads();
    if (tid == 0) carry = cb + total;
    __syncthreads();
  }
}

// ---------------------------------------------------------------- GEMM (bf16 MFMA)
// C[m][n] = sum_k A[m][k] * Bt[n][k]   (both operands K-contiguous)
// Block: 256 thr = 4 waves; tile 64x64; each wave 32x32 (2x2 mfma tiles); BK=64.
// MODE 0: QKV   A=xbf[8192x1024], Bt=wqkvt plane (blockIdx.y = mat*16+h), out bf16 qkv
// MODE 1: MoE-1 A=xbf gathered via gidx, Bt=w1t[e], out bf16 H (+bias,relu), masked rows
// MODE 2: MoE-2 A=H rows [off..off+n_e), Bt=w2t[e], out bf16 Y (+bias), masked rows
template <int MODE>
__global__ __launch_bounds__(256) void gemm_bt(
    const u16* __restrict__ A, const u16* __restrict__ Bt,
    u16* __restrict__ outB, const float* __restrict__ bias,
    const int* __restrict__ meta, const int* __restrict__ gidx, int K) {
  int m0 = blockIdx.x * 64;
  int n_e = 0, off = 0, n0 = 0;
  const u16* Ap = A;
  const u16* Bp;
  if constexpr (MODE == 0) {
    Bp = Bt + (size_t)blockIdx.y * 64 * 1024;
  } else {
    int e = blockIdx.z;
    n_e = meta[e];
    off = meta[8 + e];
    if (m0 >= n_e) return;
    n0 = blockIdx.y * 64;
    if constexpr (MODE == 1) {
      Bp = Bt + (size_t)e * DFF * 1024;
    } else {
      Ap = A + (size_t)off * DFF;
      Bp = Bt + (size_t)e * 1024 * DFF;
    }
  }

  __shared__ __align__(16) u16 As[64 * 72];
  __shared__ __align__(16) u16 Bs[64 * 72];
  int tid = threadIdx.x, lane = tid & 63, wave = tid >> 6;
  int wm = wave >> 1, wn = wave & 1, ml = lane & 15, quad = lane >> 4;
  f4 acc[2][2];
#pragma unroll
  for (int i = 0; i < 2; ++i)
#pragma unroll
    for (int j = 0; j < 2; ++j) acc[i][j] = (f4){0.f, 0.f, 0.f, 0.f};

  for (int k0 = 0; k0 < K; k0 += 64) {
#pragma unroll
    for (int it = 0; it < 2; ++it) {
      int i = it * 256 + tid;           // 0..511
      int r = i >> 3, c = (i & 7) * 8;  // 64 rows x 8 chunks of 8 bf16
      const u16* sa;
      if constexpr (MODE == 1) {
        int rr = m0 + r; if (rr >= n_e) rr = n_e - 1;
        sa = Ap + (size_t)gidx[off + rr] * 1024 + k0 + c;
      } else if constexpr (MODE == 2) {
        int rr = m0 + r; if (rr >= n_e) rr = n_e - 1;
        sa = Ap + (size_t)rr * DFF + k0 + c;
      } else {
        sa = Ap + (size_t)(m0 + r) * 1024 + k0 + c;
      }
      *(uint4*)(&As[r * 72 + c]) = *(const uint4*)sa;
      const u16* sb = Bp + (size_t)(n0 + r) * K + k0 + c;
      *(uint4*)(&Bs[r * 72 + c]) = *(const uint4*)sb;
    }
    __syncthreads();
#pragma unroll
    for (int kk = 0; kk < 64; kk += 32) {
      bf8 a0 = *(const bf8*)(&As[(wm * 32 + ml) * 72 + kk + quad * 8]);
      bf8 a1 = *(const bf8*)(&As[(wm * 32 + 16 + ml) * 72 + kk + quad * 8]);
      bf8 b0 = *(const bf8*)(&Bs[(wn * 32 + ml) * 72 + kk + quad * 8]);
      bf8 b1 = *(const bf8*)(&Bs[(wn * 32 + 16 + ml) * 72 + kk + quad * 8]);
      acc[0][0] = mfma16(a0, b0, acc[0][0]);
      acc[0][1] = mfma16(a0, b1, acc[0][1]);
      acc[1][0] = mfma16(a1, b0, acc[1][0]);
      acc[1][1] = mfma16(a1, b1, acc[1][1]);
    }
    __syncthreads();
  }

#pragma unroll
  for (int mi = 0; mi < 2; ++mi)
#pragma unroll
    for (int ni = 0; ni < 2; ++ni)
#pragma unroll
      for (int rg = 0; rg < 4; ++rg) {
        int rl = wm * 32 + mi * 16 + quad * 4 + rg;  // row within tile
        int cl = wn * 32 + ni * 16 + ml;             // col within tile
        float v = acc[mi][ni][rg];
        if constexpr (MODE == 0) {
          outB[(size_t)blockIdx.y * NTOK * HS_ + (size_t)(m0 + rl) * HS_ + cl] = f2bf(v);
        } else if constexpr (MODE == 1) {
          int r = m0 + rl;
          if (r < n_e) {
            int gc = n0 + cl;
            float hv = v + bias[blockIdx.z * DFF + gc];
            hv = fmaxf(hv, 0.f);
            outB[(size_t)(off + r) * DFF + gc] = f2bf(hv);
          }
        } else {
          int r = m0 + rl;
          if (r < n_e) {
            int gc = n0 + cl;
            outB[(size_t)(off + r) * 1024 + gc] = f2bf(v + bias[blockIdx.z * 1024 + gc]);
          }
        }
      }
}

// ---------------------------------------------------------------- attention (fp32 flash)
// block = 256 thr, Q-tile 64 rows, K/V chunks of 32, online softmax.
// thread (ty,tx): ty=tid>>4 owns rows ty*4+ri ; tx=tid&15 owns S-cols tx*2+jj, O-cols tx*4+ci
__global__ __launch_bounds__(256) void attn_kernel(const u16* __restrict__ qkv,
                                                   float* __restrict__ attn_out) {
  int qt = blockIdx.x, bh = blockIdx.y;
  int b = bh >> 4, h = bh & 15;
  int q0 = qt * 64;
  const size_t plane = (size_t)NTOK * HS_;
  const u16* Qg = qkv + (size_t)h * plane + (size_t)b * T_ * HS_;
  const u16* Kg = qkv + (size_t)(16 + h) * plane + (size_t)b * T_ * HS_;
  const u16* Vg = qkv + (size_t)(32 + h) * plane + (size_t)b * T_ * HS_;
  __shared__ float Qs[64][65];
  __shared__ float Ks[32][65];
  __shared__ float Vs[32][65];
  __shared__ float Ps[64][33];
  int tid = threadIdx.x;
  int tx = tid & 15, ty = tid >> 4;

  for (int i = tid; i < 1024; i += 256) {  // 64x64 in 4-elem chunks
    int row = i >> 4, c4 = (i & 15) * 4;
    uint2 u = *(const uint2*)(Qg + (size_t)(q0 + row) * HS_ + c4);
    Qs[row][c4 + 0] = bf2f((u16)(u.x & 0xffff));
    Qs[row][c4 + 1] = bf2f((u16)(u.x >> 16));
    Qs[row][c4 + 2] = bf2f((u16)(u.y & 0xffff));
    Qs[row][c4 + 3] = bf2f((u16)(u.y >> 16));
  }

  float m_[4], l_[4], o_[4][4];
#pragma unroll
  for (int ri = 0; ri < 4; ++ri) {
    m_[ri] = -1e30f; l_[ri] = 0.f;
#pragma unroll
    for (int ci = 0; ci < 4; ++ci) o_[ri][ci] = 0.f;
  }

  int nkv = (q0 + 64) >> 5;
  for (int ck = 0; ck < nkv; ++ck) {
    int kv0 = ck << 5;
    __syncthreads();  // protect Ks/Vs/Ps from previous iteration's readers
    for (int i = tid; i < 512; i += 256) {  // 32x64 each for K and V
      int row = i >> 4, c4 = (i & 15) * 4;
      uint2 uk = *(const uint2*)(Kg + (size_t)(kv0 + row) * HS_ + c4);
      uint2 uv = *(const uint2*)(Vg + (size_t)(kv0 + row) * HS_ + c4);
      Ks[row][c4 + 0] = bf2f((u16)(uk.x & 0xffff));
      Ks[row][c4 + 1] = bf2f((u16)(uk.x >> 16));
      Ks[row][c4 + 2] = bf2f((u16)(uk.y & 0xffff));
      Ks[row][c4 + 3] = bf2f((u16)(uk.y >> 16));
      Vs[row][c4 + 0] = bf2f((u16)(uv.x & 0xffff));
      Vs[row][c4 + 1] = bf2f((u16)(uv.x >> 16));
      Vs[row][c4 + 2] = bf2f((u16)(uv.y & 0xffff));
      Vs[row][c4 + 3] = bf2f((u16)(uv.y >> 16));
    }
    __syncthreads();

    float s[4][2] = {{0.f, 0.f}, {0.f, 0.f}, {0.f, 0.f}, {0.f, 0.f}};
    for (int e = 0; e < HS_; ++e) {
      float k0v = Ks[tx * 2 + 0][e], k1v = Ks[tx * 2 + 1][e];
#pragma unroll
      for (int ri = 0; ri < 4; ++ri) {
        float qv = Qs[ty * 4 + ri][e];
        s[ri][0] += qv * k0v;
        s[ri][1] += qv * k1v;
      }
    }
    bool need_mask = (kv0 + 31 > q0);
    float mx[4];
#pragma unroll
    for (int ri = 0; ri < 4; ++ri) {
      s[ri][0] *= 0.03125f;  // D^-0.5
      s[ri][1] *= 0.03125f;
      if (need_mask) {
        int gi = q0 + ty * 4 + ri;
        if (kv0 + tx * 2 + 0 > gi) s[ri][0] = -1e30f;
        if (kv0 + tx * 2 + 1 > gi) s[ri][1] = -1e30f;
      }
      mx[ri] = fmaxf(s[ri][0], s[ri][1]);
    }
#pragma unroll
    for (int off = 1; off < 16; off <<= 1)
#pragma unroll
      for (int ri = 0; ri < 4; ++ri) mx[ri] = fmaxf(mx[ri], __shfl_xor(mx[ri], off));

    float p[4][2], rs[4], al[4];
#pragma unroll
    for (int ri = 0; ri < 4; ++ri) {
      float mn = fmaxf(m_[ri], mx[ri]);
      al[ri] = __expf(m_[ri] - mn);
      m_[ri] = mn;
      p[ri][0] = __expf(s[ri][0] - mn);
      p[ri][1] = __expf(s[ri][1] - mn);
      rs[ri] = p[ri][0] + p[ri][1];
    }
#pragma unroll
    for (int off = 1; off < 16; off <<= 1)
#pragma unroll
      for (int ri = 0; ri < 4; ++ri) rs[ri] += __shfl_xor(rs[ri], off);
#pragma unroll
    for (int ri = 0; ri < 4; ++ri) {
      l_[ri] = al[ri] * l_[ri] + rs[ri];
#pragma unroll
      for (int ci = 0; ci < 4; ++ci) o_[ri][ci] *= al[ri];
      Ps[ty * 4 + ri][tx * 2 + 0] = p[ri][0];
      Ps[ty * 4 + ri][tx * 2 + 1] = p[ri][1];
    }
    __syncthreads();
    for (int j = 0; j < 32; ++j) {
      float v0 = Vs[j][tx * 4 + 0], v1 = Vs[j][tx * 4 + 1];
      float v2 = Vs[j][tx * 4 + 2], v3 = Vs[j][tx * 4 + 3];
#pragma unroll
      for (int ri = 0; ri < 4; ++ri) {
        float pv = Ps[ty * 4 + ri][j];
        o_[ri][0] += pv * v0;
        o_[ri][1] += pv * v1;
        o_[ri][2] += pv * v2;
        o_[ri][3] += pv * v3;
      }
    }
  }
#pragma unroll
  for (int ri = 0; ri < 4; ++ri) {
    float inv = 1.f / l_[ri];
    float4 o4;
    o4.x = o_[ri][0] * inv; o4.y = o_[ri][1] * inv;
    o4.z = o_[ri][2] * inv; o4.w = o_[ri][3] * inv;
    *(float4*)(attn_out + (size_t)(b * T_ + q0 + ty * 4 + ri) * D_ + h * HS_ + tx * 4) = o4;
  }
}

// ---------------------------------------------------------------- final: out = x + LN(attn) + LN(moe)
__global__ __launch_bounds__(256) void final_kernel(
    const float* __restrict__ x, const float* __restrict__ attn,
    const u16* __restrict__ Y, const int* __restrict__ rowmap,
    const float* __restrict__ wgt,
    const float* __restrict__ g1, const float* __restrict__ be1,
    const float* __restrict__ g2, const float* __restrict__ be2,
    float* __restrict__ out) {
  int t = blockIdx.x, tid = threadIdx.x;
  int lane = tid & 63, wave = tid >> 6;
  float4 av = ((const float4*)(attn + (size_t)t * D_))[tid];
  int r0 = rowmap[2 * t], r1 = rowmap[2 * t + 1];
  float w0 = wgt[2 * t], w1 = wgt[2 * t + 1];
  ushort4 y0 = ((const ushort4*)(Y + (size_t)r0 * D_))[tid];
  ushort4 y1 = ((const ushort4*)(Y + (size_t)r1 * D_))[tid];
  float4 mv;
  mv.x = w0 * bf2f(y0.x) + w1 * bf2f(y1.x);
  mv.y = w0 * bf2f(y0.y) + w1 * bf2f(y1.y);
  mv.z = w0 * bf2f(y0.z) + w1 * bf2f(y1.z);
  mv.w = w0 * bf2f(y0.w) + w1 * bf2f(y1.w);

  float sa = av.x + av.y + av.z + av.w;
  float qa = av.x * av.x + av.y * av.y + av.z * av.z + av.w * av.w;
  float sm = mv.x + mv.y + mv.z + mv.w;
  float qm = mv.x * mv.x + mv.y * mv.y + mv.z * mv.z + mv.w * mv.w;
#pragma unroll
  for (int off = 1; off < 64; off <<= 1) {
    sa += __shfl_xor(sa, off);
    qa += __shfl_xor(qa, off);
    sm += __shfl_xor(sm, off);
    qm += __shfl_xor(qm, off);
  }
  __shared__ float red[4][4];
  if (lane == 0) { red[wave][0] = sa; red[wave][1] = qa; red[wave][2] = sm; red[wave][3] = qm; }
  __syncthreads();
  sa = red[0][0] + red[1][0] + red[2][0] + red[3][0];
  qa = red[0][1] + red[1][1] + red[2][1] + red[3][1];
  sm = red[0][2] + red[1][2] + red[2][2] + red[3][2];
  qm = red[0][3] + red[1][3] + red[2][3] + red[3][3];
  const float inv_d = 1.f / 1024.f;
  float mu1 = sa * inv_d, var1 = qa * inv_d - mu1 * mu1;
  float mu2 = sm * inv_d, var2 = qm * inv_d - mu2 * mu2;
  float rs1 = rsqrtf(var1 + 1e-5f), rs2 = rsqrtf(var2 + 1e-5f);

  float4 xv = ((const float4*)(x + (size_t)t * D_))[tid];
  float4 g1v = ((const float4*)g1)[tid], b1v = ((const float4*)be1)[tid];
  float4 g2v = ((const float4*)g2)[tid], b2v = ((const float4*)be2)[tid];
  float4 o;
  o.x = xv.x + (av.x - mu1) * rs1 * g1v.x + b1v.x + (mv.x - mu2) * rs2 * g2v.x + b2v.x;
  o.y = xv.y + (av.y - mu1) * rs1 * g1v.y + b1v.y + (mv.y - mu2) * rs2 * g2v.y + b2v.y;
  o.z = xv.z + (av.z - mu1) * rs1 * g1v.z + b1v.z + (mv.z - mu2) * rs2 * g2v.z + b2v.z;
  o.w = xv.w + (av.w - mu1) * rs1 * g1v.w + b1v.w + (mv.w - mu2) * rs2 * g2v.w + b2v.w;
  ((float4*)(out + (size_t)t * D_))[tid] = o;
}

// ---------------------------------------------------------------- launch
extern "C" void kernel_launch(void* const* d_in, const int* in_sizes, int n_in,
                              void* d_out, int out_size, void* d_ws, size_t ws_size,
                              hipStream_t stream) {
  const float* x   = (const float*)d_in[0];
  const float* Wq  = (const float*)d_in[1];
  const float* Wk  = (const float*)d_in[2];
  const float* Wv  = (const float*)d_in[3];
  const float* Wg  = (const float*)d_in[4];
  const float* W1  = (const float*)d_in[5];
  const float* b1  = (const float*)d_in[6];
  const float* W2  = (const float*)d_in[7];
  const float* b2  = (const float*)d_in[8];
  const float* g1  = (const float*)d_in[9];
  const float* be1 = (const float*)d_in[10];
  const float* g2  = (const float*)d_in[11];
  const float* be2 = (const float*)d_in[12];
  float* out = (float*)d_out;

  char* ws = (char*)d_ws;
  size_t off = 0;
  auto alloc = [&](size_t bytes) -> void* {
    void* p = ws + off;
    off = (off + bytes + 255) & ~(size_t)255;
    return p;
  };
  u16*   xbf    = (u16*)alloc((size_t)NTOK * D_ * 2);          // 16.8 MB
  u16*   wqkvt  = (u16*)alloc((size_t)48 * 64 * 1024 * 2);     // 6.3 MB  [mat*16+h][64][1024]
  u16*   w1t    = (u16*)alloc((size_t)E_ * DFF * 1024 * 2);    // 67 MB   [e][4096][1024]
  u16*   w2t    = (u16*)alloc((size_t)E_ * 1024 * DFF * 2);    // 67 MB   [e][1024][4096]
  u16*   qkv    = (u16*)alloc((size_t)48 * NTOK * HS_ * 2);    // 50 MB   [mat*16+h][8192][64]
  float* attn   = (float*)alloc((size_t)NTOK * D_ * 4);        // 33.5 MB
  u16*   Hbuf   = (u16*)alloc((size_t)NROW * DFF * 2);         // 134 MB
  u16*   Ybuf   = (u16*)alloc((size_t)NROW * 1024 * 2);        // 33.5 MB
  int*   meta   = (int*)alloc(256);
  int*   sel    = (int*)alloc(NROW * 4);
  float* wgt    = (float*)alloc(NROW * 4);
  int*   gidx   = (int*)alloc(NROW * 4);
  float* gw     = (float*)alloc(NROW * 4);
  int*   rowmap = (int*)alloc(NROW * 4);
  (void)ws_size; (void)in_sizes; (void)n_in; (void)out_size; (void)gw;

  // dtype converts / transposes (weights -> bf16, K-contiguous "B^T" layout)
  cvt_x_kernel<<<NTOK * D_ / 1024, 256, 0, stream>>>(x, xbf);
  transpose_cvt_kernel<<<dim3(32, 2, 16), 256, 0, stream>>>(Wq, wqkvt, 1024, 64, 65536, 65536);
  transpose_cvt_kernel<<<dim3(32, 2, 16), 256, 0, stream>>>(Wk, wqkvt + 16 * 65536, 1024, 64, 65536, 65536);
  transpose_cvt_kernel<<<dim3(32, 2, 16), 256, 0, stream>>>(Wv, wqkvt + 32 * 65536, 1024, 64, 65536, 65536);
  transpose_cvt_kernel<<<dim3(32, 128, 8), 256, 0, stream>>>(W1, w1t, 1024, 4096, (size_t)1024 * 4096, (size_t)1024 * 4096);
  transpose_cvt_kernel<<<dim3(128, 32, 8), 256, 0, stream>>>(W2, w2t, 4096, 1024, (size_t)4096 * 1024, (size_t)4096 * 1024);

  // routing
  gating_kernel<<<NTOK / 4, 256, 0, stream>>>(x, Wg, sel, wgt);
  offsets_kernel<<<1, 256, 0, stream>>>(sel, meta);
  assign_kernel<<<E_, 256, 0, stream>>>(sel, wgt, meta, gidx, gw, rowmap);

  // attention branch
  gemm_bt<0><<<dim3(128, 48), 256, 0, stream>>>(xbf, wqkvt, qkv, nullptr, nullptr, nullptr, 1024);
  attn_kernel<<<dim3(16, 128), 256, 0, stream>>>(qkv, attn);

  // MoE branch (worst-case grid, device-side early exit on counts)
  gemm_bt<1><<<dim3(128, 64, 8), 256, 0, stream>>>(xbf, w1t, Hbuf, b1, meta, gidx, 1024);
  gemm_bt<2><<<dim3(128, 16, 8), 256, 0, stream>>>(Hbuf, w2t, Ybuf, b2, meta, gidx, 4096);

  // out = x + LN(attn) + LN(moe)
  final_kernel<<<NTOK, 256, 0, stream>>>(x, attn, Ybuf, rowmap, wgt, g1, be1, g2, be2, out);
}

// Round 2
// 1715.591 us; speedup vs baseline: 1.2203x; 1.2203x over previous
//
#include <hip/hip_runtime.h>

// Problem constants
#define B_    8
#define T_    1024
#define D_    1024
#define H_    16
#define HS_   64
#define E_    8
#define DFF   4096
#define NTOK  8192    // B*T
#define NROW  16384   // NTOK * top-2

typedef unsigned short u16;
typedef unsigned int   u32;
typedef __attribute__((ext_vector_type(8))) short bf8;   // 8 bf16 in 4 VGPRs
typedef __attribute__((ext_vector_type(4))) float f4;    // MFMA accumulator

__device__ __forceinline__ u16 f2bf(float f) {
  u32 u = __float_as_uint(f);
  u32 r = (u + 0x7FFFu + ((u >> 16) & 1u)) >> 16;  // RNE
  return (u16)r;
}
__device__ __forceinline__ float bf2f(u16 h) {
  return __uint_as_float(((u32)h) << 16);
}

__device__ __forceinline__ f4 mfma16(bf8 a, bf8 b, f4 c) {
  return __builtin_amdgcn_mfma_f32_16x16x32_bf16(a, b, c, 0, 0, 0);
}

// async global->LDS, 16B per lane; LDS dest = wave-uniform base + lane*16
typedef const __attribute__((address_space(1))) void* gas_ptr;
typedef __attribute__((address_space(3))) void* las_ptr;
__device__ __forceinline__ void async16(const void* g, void* l) {
  __builtin_amdgcn_global_load_lds((gas_ptr)g, (las_ptr)l, 16, 0, 0);
}

// ---------------------------------------------------------------- converts
__global__ __launch_bounds__(256) void cvt_x_kernel(const float* __restrict__ x,
                                                    u16* __restrict__ xbf) {
  int i = blockIdx.x * 256 + threadIdx.x;  // float4 index
  float4 v = ((const float4*)x)[i];
  ushort4 o;
  o.x = f2bf(v.x); o.y = f2bf(v.y); o.z = f2bf(v.z); o.w = f2bf(v.w);
  ((ushort4*)xbf)[i] = o;
}

// src fp32 [R x C] -> dst bf16 [C x R], batched along z
__global__ __launch_bounds__(256) void transpose_cvt_kernel(
    const float* __restrict__ src, u16* __restrict__ dst,
    int R, int C, size_t sStride, size_t dStride) {
  __shared__ float t[32][33];
  src += (size_t)blockIdx.z * sStride;
  dst += (size_t)blockIdx.z * dStride;
  int r0 = blockIdx.x * 32, c0 = blockIdx.y * 32;
  int tx = threadIdx.x & 31, ty = threadIdx.x >> 5;  // ty 0..7
#pragma unroll
  for (int i = 0; i < 32; i += 8)
    t[ty + i][tx] = src[(size_t)(r0 + ty + i) * C + (c0 + tx)];
  __syncthreads();
#pragma unroll
  for (int i = 0; i < 32; i += 8)
    dst[(size_t)(c0 + ty + i) * R + (r0 + tx)] = f2bf(t[tx][ty + i]);
}

// V plane [t][c] -> Vt [bh][c][t] (bf16), for PV B-operand staging
__global__ __launch_bounds__(256) void vtrans_kernel(const u16* __restrict__ qkv,
                                                     u16* __restrict__ Vt) {
  __shared__ u16 t[32][33];
  int bh = blockIdx.z, b = bh >> 4, h = bh & 15;
  const u16* Vg = qkv + (size_t)(32 + h) * NTOK * HS_ + (size_t)b * T_ * HS_;
  u16* Vp = Vt + (size_t)bh * HS_ * T_;
  int t0 = blockIdx.x * 32, c0 = blockIdx.y * 32;
  int tx = threadIdx.x & 31, ty = threadIdx.x >> 5;
#pragma unroll
  for (int i = 0; i < 32; i += 8)
    t[ty + i][tx] = Vg[(size_t)(t0 + ty + i) * HS_ + c0 + tx];
  __syncthreads();
#pragma unroll
  for (int i = 0; i < 32; i += 8)
    Vp[(size_t)(c0 + ty + i) * T_ + t0 + tx] = t[tx][ty + i];
}

// ---------------------------------------------------------------- gating
// exact fp32 gating so top-2 selection matches the reference
__global__ __launch_bounds__(256) void gating_kernel(
    const float* __restrict__ x, const float* __restrict__ Wg,
    int* __restrict__ sel, float* __restrict__ wgt) {
  int wave = threadIdx.x >> 6, lane = threadIdx.x & 63;
  int t = blockIdx.x * 4 + wave;
  int e = lane & 7, grp = lane >> 3;
  const float* xr = x + (size_t)t * D_;
  float acc = 0.f;
  for (int i = 0; i < 128; ++i) {
    int d = grp + i * 8;
    acc += xr[d] * Wg[d * 8 + e];
  }
  acc += __shfl_xor(acc, 8);
  acc += __shfl_xor(acc, 16);
  acc += __shfl_xor(acc, 32);
  float lg[8];
#pragma unroll
  for (int j = 0; j < 8; ++j) lg[j] = __shfl(acc, j);
  int s0 = 0; float v0 = lg[0];
#pragma unroll
  for (int j = 1; j < 8; ++j) if (lg[j] > v0) { v0 = lg[j]; s0 = j; }
  int s1 = -1; float v1 = -3.4e38f;
#pragma unroll
  for (int j = 0; j < 8; ++j) if (j != s0 && lg[j] > v1) { v1 = lg[j]; s1 = j; }
  if (lane == 0) {
    float dd = __expf(v1 - v0);
    float w0 = 1.f / (1.f + dd);
    sel[2 * t]     = s0; sel[2 * t + 1] = s1;
    wgt[2 * t]     = w0; wgt[2 * t + 1] = dd * w0;
  }
}

// counts + exclusive offsets -> meta[0..7]=counts, meta[8..15]=offsets
__global__ __launch_bounds__(256) void offsets_kernel(const int* __restrict__ sel,
                                                      int* __restrict__ meta) {
  __shared__ int hist[E_];
  int tid = threadIdx.x;
  if (tid < E_) hist[tid] = 0;
  __syncthreads();
  for (int i = tid; i < NROW; i += 256) atomicAdd(&hist[sel[i]], 1);
  __syncthreads();
  if (tid == 0) {
    int s = 0;
    for (int e = 0; e < E_; ++e) { int c = hist[e]; meta[e] = c; meta[8 + e] = s; s += c; }
  }
}

// deterministic per-expert stable assignment via ballot scan
__global__ __launch_bounds__(256) void assign_kernel(
    const int* __restrict__ sel, const float* __restrict__ wgt,
    const int* __restrict__ meta, int* __restrict__ gidx,
    float* __restrict__ gw, int* __restrict__ rowmap) {
  int e = blockIdx.x, tid = threadIdx.x, lane = tid & 63, wv = tid >> 6;
  __shared__ int wsum[4];
  __shared__ int carry;
  if (tid == 0) carry = meta[8 + e];
  __syncthreads();
  for (int base = 0; base < NROW; base += 256) {
    int idx = base + tid;
    int f = (sel[idx] == e) ? 1 : 0;
    unsigned long long mask = __ballot(f);
    int pre = __popcll(mask & ((1ull << lane) - 1ull));
    if (lane == 0) wsum[wv] = __popcll(mask);
    __syncthreads();
    int woff = 0;
    for (int w = 0; w < wv; ++w) woff += wsum[w];
    int cb = carry;
    if (f) {
      int pos = cb + woff + pre;
      gidx[pos] = idx >> 1;
      gw[pos] = wgt[idx];
      rowmap[idx] = pos;
    }
    __syncthreads();
    if (tid == 0) carry = cb + wsum[0] + wsum[1] + wsum[2] + wsum[3];
    __syncthreads();
  }
}

// ---------------------------------------------------------------- GEMM (bf16 MFMA, m97-style)
// C[m][n] = sum_k A[m][k] * Bt[n][k]; tile 128x128, BK=64, 4 waves as 2x2,
// each wave 64x64 = 4x4 mfma tiles. global_load_lds width-16 staging (no pad).
// MODE 0: QKV  A=xbf[8192x1024], Bt=wqkvt[3072x1024], out planes qkv[48][8192][64]
// MODE 1: MoE1 A=xbf gathered via gidx, Bt=w1t[e], out H bf16 (+bias,relu)
// MODE 2: MoE2 A=Hbuf rows, Bt=w2t[e], out Y bf16 (+bias)
template <int MODE>
__global__ __launch_bounds__(256) void gemm_bt(
    const u16* __restrict__ A, const u16* __restrict__ Bt,
    u16* __restrict__ outB, const float* __restrict__ bias,
    const int* __restrict__ meta, const int* __restrict__ gidx, int K) {
  int m0 = blockIdx.x * 128;
  int n0 = blockIdx.y * 128;
  int n_e = 0, off = 0;
  const u16* Ap = A;
  const u16* Bp = Bt;
  if constexpr (MODE != 0) {
    int e = blockIdx.z;
    n_e = meta[e];
    off = meta[8 + e];
    if (m0 >= n_e) return;
    if constexpr (MODE == 1) {
      Bp = Bt + (size_t)e * DFF * 1024;
    } else {
      Ap = A + (size_t)off * DFF;
      Bp = Bt + (size_t)e * 1024 * DFF;
    }
  }

  __shared__ __align__(16) u16 As[128 * 64];
  __shared__ __align__(16) u16 Bs[128 * 64];
  int tid = threadIdx.x, lane = tid & 63, wave = tid >> 6;
  int wm = wave >> 1, wn = wave & 1, ml = lane & 15, quad = lane >> 4;
  int lrow = lane >> 3, lcol = (lane & 7) * 8;
  f4 acc[4][4];
#pragma unroll
  for (int i = 0; i < 4; ++i)
#pragma unroll
    for (int j = 0; j < 4; ++j) acc[i][j] = (f4){0.f, 0.f, 0.f, 0.f};

  for (int k0 = 0; k0 < K; k0 += 64) {
    __syncthreads();
#pragma unroll
    for (int r = 0; r < 4; ++r) {
      int row = wave * 32 + r * 8;  // wave-uniform LDS base row
      int ra = m0 + row + lrow;
      const u16* ga;
      if constexpr (MODE == 1) {
        int rr = ra < n_e ? ra : n_e - 1;
        ga = Ap + (size_t)gidx[off + rr] * 1024 + k0 + lcol;
      } else if constexpr (MODE == 2) {
        int rr = ra < n_e ? ra : n_e - 1;
        ga = Ap + (size_t)rr * DFF + k0 + lcol;
      } else {
        ga = Ap + (size_t)ra * 1024 + k0 + lcol;
      }
      async16(ga, &As[row * 64]);
      const u16* gb = Bp + (size_t)(n0 + row + lrow) * K + k0 + lcol;
      async16(gb, &Bs[row * 64]);
    }
    __syncthreads();  // drains vmcnt for global_load_lds
#pragma unroll
    for (int kk = 0; kk < 64; kk += 32) {
      bf8 af[4], bfr[4];
#pragma unroll
      for (int mi = 0; mi < 4; ++mi)
        af[mi] = *(const bf8*)&As[(wm * 64 + mi * 16 + ml) * 64 + kk + quad * 8];
#pragma unroll
      for (int ni = 0; ni < 4; ++ni)
        bfr[ni] = *(const bf8*)&Bs[(wn * 64 + ni * 16 + ml) * 64 + kk + quad * 8];
#pragma unroll
      for (int mi = 0; mi < 4; ++mi)
#pragma unroll
        for (int ni = 0; ni < 4; ++ni)
          acc[mi][ni] = mfma16(af[mi], bfr[ni], acc[mi][ni]);
    }
  }

#pragma unroll
  for (int mi = 0; mi < 4; ++mi)
#pragma unroll
    for (int ni = 0; ni < 4; ++ni)
#pragma unroll
      for (int rg = 0; rg < 4; ++rg) {
        int m = m0 + wm * 64 + mi * 16 + quad * 4 + rg;
        int n = n0 + wn * 64 + ni * 16 + ml;
        float v = acc[mi][ni][rg];
        if constexpr (MODE == 0) {
          int p = n >> 6, col = n & 63;
          outB[(size_t)p * NTOK * HS_ + (size_t)m * HS_ + col] = f2bf(v);
        } else if constexpr (MODE == 1) {
          if (m < n_e) {
            float hv = v + bias[blockIdx.z * DFF + n];
            outB[(size_t)(off + m) * DFF + n] = f2bf(fmaxf(hv, 0.f));
          }
        } else {
          if (m < n_e) {
            outB[(size_t)(off + m) * 1024 + n] = f2bf(v + bias[blockIdx.z * 1024 + n]);
          }
        }
      }
}

// ---------------------------------------------------------------- attention (bf16 MFMA flash)
// block 256 = 4 waves; Q tile 64 rows (wave w owns rows w*16..), KV chunks of 64.
// S via mfma (C-layout) -> online softmax (16-lane shfl rows) -> P to wave-private
// LDS strip (A-layout) -> PV via mfma with pre-transposed V.
__global__ __launch_bounds__(256) void attn_kernel(const u16* __restrict__ qkv,
                                                   const u16* __restrict__ Vt,
                                                   float* __restrict__ attn_out) {
  int qt = blockIdx.x, bh = blockIdx.y;
  int b = bh >> 4, h = bh & 15;
  int q0 = qt * 64;
  const u16* Qg = qkv + (size_t)h * NTOK * HS_ + (size_t)b * T_ * HS_;
  const u16* Kg = qkv + (size_t)(16 + h) * NTOK * HS_ + (size_t)b * T_ * HS_;
  const u16* Vp = Vt + (size_t)bh * HS_ * T_;
  __shared__ __align__(16) u16 Qs[64 * 72];
  __shared__ __align__(16) u16 Ks[64 * 72];
  __shared__ __align__(16) u16 Vs[64 * 72];   // Vs[c][j]
  __shared__ __align__(16) u16 Ps[64 * 72];   // wave w uses rows w*16..w*16+15
  int tid = threadIdx.x, lane = tid & 63, wave = tid >> 6;
  int ml = lane & 15, quad = lane >> 4;

  for (int i = tid; i < 512; i += 256) {
    int r = i >> 3, c = (i & 7) * 8;
    *(uint4*)&Qs[r * 72 + c] = *(const uint4*)(Qg + (size_t)(q0 + r) * HS_ + c);
  }

  f4 acc_o[4];
  float m_[4], l_[4];
#pragma unroll
  for (int i = 0; i < 4; ++i) {
    acc_o[i] = (f4){0.f, 0.f, 0.f, 0.f};
    m_[i] = -1e30f; l_[i] = 0.f;
  }

  for (int ck = 0; ck <= qt; ++ck) {
    int kv0 = ck * 64;
    __syncthreads();
    for (int i = tid; i < 512; i += 256) {
      int r = i >> 3, c = (i & 7) * 8;
      *(uint4*)&Ks[r * 72 + c] = *(const uint4*)(Kg + (size_t)(kv0 + r) * HS_ + c);
      *(uint4*)&Vs[r * 72 + c] = *(const uint4*)(Vp + (size_t)r * T_ + kv0 + c);
    }
    __syncthreads();

    // S = Q K^T (16x64 per wave)
    f4 sacc[4];
#pragma unroll
    for (int nt = 0; nt < 4; ++nt) sacc[nt] = (f4){0.f, 0.f, 0.f, 0.f};
#pragma unroll
    for (int kk = 0; kk < 64; kk += 32) {
      bf8 a = *(const bf8*)&Qs[(wave * 16 + ml) * 72 + kk + quad * 8];
#pragma unroll
      for (int nt = 0; nt < 4; ++nt) {
        bf8 bk = *(const bf8*)&Ks[(nt * 16 + ml) * 72 + kk + quad * 8];
        sacc[nt] = mfma16(a, bk, sacc[nt]);
      }
    }

    // online softmax; C-layout: row = quad*4+rg (strip-local), col = nt*16+ml
    bool dm = (kv0 == q0);  // only the diagonal chunk needs masking
    float pv[4][4], mx[4];
#pragma unroll
    for (int rg = 0; rg < 4; ++rg) {
      int gq = q0 + wave * 16 + quad * 4 + rg;
      float mm = -1e30f;
#pragma unroll
      for (int nt = 0; nt < 4; ++nt) {
        float s = sacc[nt][rg] * 0.03125f;  // D^-0.5
        if (dm && (kv0 + nt * 16 + ml) > gq) s = -1e30f;
        pv[nt][rg] = s;
        mm = fmaxf(mm, s);
      }
      mx[rg] = mm;
    }
#pragma unroll
    for (int off = 1; off < 16; off <<= 1)
#pragma unroll
      for (int rg = 0; rg < 4; ++rg) mx[rg] = fmaxf(mx[rg], __shfl_xor(mx[rg], off));

    float al[4], rs[4];
#pragma unroll
    for (int rg = 0; rg < 4; ++rg) {
      float mn = fmaxf(m_[rg], mx[rg]);
      al[rg] = __expf(m_[rg] - mn);
      m_[rg] = mn;
      float r = 0.f;
#pragma unroll
      for (int nt = 0; nt < 4; ++nt) {
        float e = __expf(pv[nt][rg] - mn);
        pv[nt][rg] = e;
        r += e;
      }
      rs[rg] = r;
    }
#pragma unroll
    for (int off = 1; off < 16; off <<= 1)
#pragma unroll
      for (int rg = 0; rg < 4; ++rg) rs[rg] += __shfl_xor(rs[rg], off);

#pragma unroll
    for (int rg = 0; rg < 4; ++rg) {
      l_[rg] = al[rg] * l_[rg] + rs[rg];
#pragma unroll
      for (int nt = 0; nt < 4; ++nt) {
        acc_o[nt][rg] *= al[rg];
        Ps[(wave * 16 + quad * 4 + rg) * 72 + nt * 16 + ml] = f2bf(pv[nt][rg]);
      }
    }

    // PV: A = Ps strip (wave-local; in-wave LDS ordering suffices), B = Vs
#pragma unroll
    for (int kk = 0; kk < 64; kk += 32) {
      bf8 a = *(const bf8*)&Ps[(wave * 16 + ml) * 72 + kk + quad * 8];
#pragma unroll
      for (int ci = 0; ci < 4; ++ci) {
        bf8 bv = *(const bf8*)&Vs[(ci * 16 + ml) * 72 + kk + quad * 8];
        acc_o[ci] = mfma16(a, bv, acc_o[ci]);
      }
    }
  }

#pragma unroll
  for (int rg = 0; rg < 4; ++rg) {
    float inv = 1.f / l_[rg];
    int gq = q0 + wave * 16 + quad * 4 + rg;
    float* orow = attn_out + (size_t)(b * T_ + gq) * D_ + h * HS_;
#pragma unroll
    for (int ci = 0; ci < 4; ++ci) orow[ci * 16 + ml] = acc_o[ci][rg] * inv;
  }
}

// ---------------------------------------------------------------- final: out = x + LN(attn) + LN(moe)
__global__ __launch_bounds__(256) void final_kernel(
    const float* __restrict__ x, const float* __restrict__ attn,
    const u16* __restrict__ Y, const int* __restrict__ rowmap,
    const float* __restrict__ wgt,
    const float* __restrict__ g1, const float* __restrict__ be1,
    const float* __restrict__ g2, const float* __restrict__ be2,
    float* __restrict__ out) {
  int t = blockIdx.x, tid = threadIdx.x;
  int lane = tid & 63, wave = tid >> 6;
  float4 av = ((const float4*)(attn + (size_t)t * D_))[tid];
  int r0 = rowmap[2 * t], r1 = rowmap[2 * t + 1];
  float w0 = wgt[2 * t], w1 = wgt[2 * t + 1];
  ushort4 y0 = ((const ushort4*)(Y + (size_t)r0 * D_))[tid];
  ushort4 y1 = ((const ushort4*)(Y + (size_t)r1 * D_))[tid];
  float4 mv;
  mv.x = w0 * bf2f(y0.x) + w1 * bf2f(y1.x);
  mv.y = w0 * bf2f(y0.y) + w1 * bf2f(y1.y);
  mv.z = w0 * bf2f(y0.z) + w1 * bf2f(y1.z);
  mv.w = w0 * bf2f(y0.w) + w1 * bf2f(y1.w);

  float sa = av.x + av.y + av.z + av.w;
  float qa = av.x * av.x + av.y * av.y + av.z * av.z + av.w * av.w;
  float sm = mv.x + mv.y + mv.z + mv.w;
  float qm = mv.x * mv.x + mv.y * mv.y + mv.z * mv.z + mv.w * mv.w;
#pragma unroll
  for (int off = 1; off < 64; off <<= 1) {
    sa += __shfl_xor(sa, off);
    qa += __shfl_xor(qa, off);
    sm += __shfl_xor(sm, off);
    qm += __shfl_xor(qm, off);
  }
  __shared__ float red[4][4];
  if (lane == 0) { red[wave][0] = sa; red[wave][1] = qa; red[wave][2] = sm; red[wave][3] = qm; }
  __syncthreads();
  sa = red[0][0] + red[1][0] + red[2][0] + red[3][0];
  qa = red[0][1] + red[1][1] + red[2][1] + red[3][1];
  sm = red[0][2] + red[1][2] + red[2][2] + red[3][2];
  qm = red[0][3] + red[1][3] + red[2][3] + red[3][3];
  const float inv_d = 1.f / 1024.f;
  float mu1 = sa * inv_d, var1 = qa * inv_d - mu1 * mu1;
  float mu2 = sm * inv_d, var2 = qm * inv_d - mu2 * mu2;
  float rs1 = rsqrtf(var1 + 1e-5f), rs2 = rsqrtf(var2 + 1e-5f);

  float4 xv = ((const float4*)(x + (size_t)t * D_))[tid];
  float4 g1v = ((const float4*)g1)[tid], b1v = ((const float4*)be1)[tid];
  float4 g2v = ((const float4*)g2)[tid], b2v = ((const float4*)be2)[tid];
  float4 o;
  o.x = xv.x + (av.x - mu1) * rs1 * g1v.x + b1v.x + (mv.x - mu2) * rs2 * g2v.x + b2v.x;
  o.y = xv.y + (av.y - mu1) * rs1 * g1v.y + b1v.y + (mv.y - mu2) * rs2 * g2v.y + b2v.y;
  o.z = xv.z + (av.z - mu1) * rs1 * g1v.z + b1v.z + (mv.z - mu2) * rs2 * g2v.z + b2v.z;
  o.w = xv.w + (av.w - mu1) * rs1 * g1v.w + b1v.w + (mv.w - mu2) * rs2 * g2v.w + b2v.w;
  ((float4*)(out + (size_t)t * D_))[tid] = o;
}

// ---------------------------------------------------------------- launch
extern "C" void kernel_launch(void* const* d_in, const int* in_sizes, int n_in,
                              void* d_out, int out_size, void* d_ws, size_t ws_size,
                              hipStream_t stream) {
  const float* x   = (const float*)d_in[0];
  const float* Wq  = (const float*)d_in[1];
  const float* Wk  = (const float*)d_in[2];
  const float* Wv  = (const float*)d_in[3];
  const float* Wg  = (const float*)d_in[4];
  const float* W1  = (const float*)d_in[5];
  const float* b1  = (const float*)d_in[6];
  const float* W2  = (const float*)d_in[7];
  const float* b2  = (const float*)d_in[8];
  const float* g1  = (const float*)d_in[9];
  const float* be1 = (const float*)d_in[10];
  const float* g2  = (const float*)d_in[11];
  const float* be2 = (const float*)d_in[12];
  float* out = (float*)d_out;

  char* ws = (char*)d_ws;
  size_t off = 0;
  auto alloc = [&](size_t bytes) -> void* {
    void* p = ws + off;
    off = (off + bytes + 255) & ~(size_t)255;
    return p;
  };
  u16*   xbf    = (u16*)alloc((size_t)NTOK * D_ * 2);          // 16.8 MB
  u16*   wqkvt  = (u16*)alloc((size_t)48 * 64 * 1024 * 2);     // 6.3 MB  [mat*16+h][64][1024] == [3072][1024]
  u16*   w1t    = (u16*)alloc((size_t)E_ * DFF * 1024 * 2);    // 67 MB   [e][4096][1024]
  u16*   w2t    = (u16*)alloc((size_t)E_ * 1024 * DFF * 2);    // 67 MB   [e][1024][4096]
  u16*   qkv    = (u16*)alloc((size_t)48 * NTOK * HS_ * 2);    // 50 MB   [mat*16+h][8192][64]
  float* attn   = (float*)alloc((size_t)NTOK * D_ * 4);        // 33.5 MB
  u16*   Hbuf   = (u16*)alloc((size_t)NROW * DFF * 2);         // 134 MB
  u16*   Ybuf   = (u16*)alloc((size_t)NROW * 1024 * 2);        // 33.5 MB
  int*   meta   = (int*)alloc(256);
  int*   sel    = (int*)alloc(NROW * 4);
  float* wgt    = (float*)alloc(NROW * 4);
  int*   gidx   = (int*)alloc(NROW * 4);
  float* gw     = (float*)alloc(NROW * 4);
  int*   rowmap = (int*)alloc(NROW * 4);
  // Vt aliases Hbuf: Vt is consumed by attn_kernel, which completes (serial
  // stream) before gemm_bt<1> writes Hbuf.
  u16*   Vt     = Hbuf;  // 16.7 MB [bh][64][1024]
  (void)ws_size; (void)in_sizes; (void)n_in; (void)out_size; (void)gw;

  // dtype converts / transposes (weights -> bf16, K-contiguous "B^T" layout)
  cvt_x_kernel<<<NTOK * D_ / 1024, 256, 0, stream>>>(x, xbf);
  transpose_cvt_kernel<<<dim3(32, 2, 16), 256, 0, stream>>>(Wq, wqkvt, 1024, 64, 65536, 65536);
  transpose_cvt_kernel<<<dim3(32, 2, 16), 256, 0, stream>>>(Wk, wqkvt + 16 * 65536, 1024, 64, 65536, 65536);
  transpose_cvt_kernel<<<dim3(32, 2, 16), 256, 0, stream>>>(Wv, wqkvt + 32 * 65536, 1024, 64, 65536, 65536);
  transpose_cvt_kernel<<<dim3(32, 128, 8), 256, 0, stream>>>(W1, w1t, 1024, 4096, (size_t)1024 * 4096, (size_t)1024 * 4096);
  transpose_cvt_kernel<<<dim3(128, 32, 8), 256, 0, stream>>>(W2, w2t, 4096, 1024, (size_t)4096 * 1024, (size_t)4096 * 1024);

  // routing
  gating_kernel<<<NTOK / 4, 256, 0, stream>>>(x, Wg, sel, wgt);
  offsets_kernel<<<1, 256, 0, stream>>>(sel, meta);
  assign_kernel<<<E_, 256, 0, stream>>>(sel, wgt, meta, gidx, gw, rowmap);

  // attention branch: QKV as one 8192x3072x1024 GEMM, then V transpose, then flash
  gemm_bt<0><<<dim3(64, 24), 256, 0, stream>>>(xbf, wqkvt, qkv, nullptr, nullptr, nullptr, 1024);
  vtrans_kernel<<<dim3(32, 2, 128), 256, 0, stream>>>(qkv, Vt);
  attn_kernel<<<dim3(16, 128), 256, 0, stream>>>(qkv, Vt, attn);

  // MoE branch (worst-case grid, device-side early exit on counts)
  gemm_bt<1><<<dim3(128, 32, 8), 256, 0, stream>>>(xbf, w1t, Hbuf, b1, meta, gidx, 1024);
  gemm_bt<2><<<dim3(128, 8, 8), 256, 0, stream>>>(Hbuf, w2t, Ybuf, b2, meta, gidx, 4096);

  // out = x + LN(attn) + LN(moe)
  final_kernel<<<NTOK, 256, 0, stream>>>(x, attn, Ybuf, rowmap, wgt, g1, be1, g2, be2, out);
}

// Round 3
// 1116.759 us; speedup vs baseline: 1.8747x; 1.5362x over previous
//
#include <hip/hip_runtime.h>

// Problem constants
#define B_    8
#define T_    1024
#define D_    1024
#define H_    16
#define HS_   64
#define E_    8
#define DFF   4096
#define NTOK  8192    // B*T
#define NROW  16384   // NTOK * top-2

typedef unsigned short u16;
typedef unsigned int   u32;
typedef __attribute__((ext_vector_type(8))) short bf8;   // 8 bf16 in 4 VGPRs
typedef __attribute__((ext_vector_type(4))) float f4;    // MFMA accumulator

__device__ __forceinline__ u16 f2bf(float f) {
  u32 u = __float_as_uint(f);
  u32 r = (u + 0x7FFFu + ((u >> 16) & 1u)) >> 16;  // RNE
  return (u16)r;
}
__device__ __forceinline__ float bf2f(u16 h) {
  return __uint_as_float(((u32)h) << 16);
}

__device__ __forceinline__ f4 mfma16(bf8 a, bf8 b, f4 c) {
  return __builtin_amdgcn_mfma_f32_16x16x32_bf16(a, b, c, 0, 0, 0);
}

// async global->LDS, 16B per lane; LDS dest = wave-uniform base + lane*16
typedef const __attribute__((address_space(1))) void* gas_ptr;
typedef __attribute__((address_space(3))) void* las_ptr;
__device__ __forceinline__ void async16(const void* g, void* l) {
  __builtin_amdgcn_global_load_lds((gas_ptr)g, (las_ptr)l, 16, 0, 0);
}

// ---------------------------------------------------------------- converts
__global__ __launch_bounds__(256) void cvt_x_kernel(const float* __restrict__ x,
                                                    u16* __restrict__ xbf) {
  int i = blockIdx.x * 256 + threadIdx.x;  // float4 index
  float4 v = ((const float4*)x)[i];
  ushort4 o;
  o.x = f2bf(v.x); o.y = f2bf(v.y); o.z = f2bf(v.z); o.w = f2bf(v.w);
  ((ushort4*)xbf)[i] = o;
}

// src fp32 [R x C] -> dst bf16 [C x R], batched along z
__global__ __launch_bounds__(256) void transpose_cvt_kernel(
    const float* __restrict__ src, u16* __restrict__ dst,
    int R, int C, size_t sStride, size_t dStride) {
  __shared__ float t[32][33];
  src += (size_t)blockIdx.z * sStride;
  dst += (size_t)blockIdx.z * dStride;
  int r0 = blockIdx.x * 32, c0 = blockIdx.y * 32;
  int tx = threadIdx.x & 31, ty = threadIdx.x >> 5;  // ty 0..7
#pragma unroll
  for (int i = 0; i < 32; i += 8)
    t[ty + i][tx] = src[(size_t)(r0 + ty + i) * C + (c0 + tx)];
  __syncthreads();
#pragma unroll
  for (int i = 0; i < 32; i += 8)
    dst[(size_t)(c0 + ty + i) * R + (r0 + tx)] = f2bf(t[tx][ty + i]);
}

// V plane [t][c] -> Vt [bh][c][t] (bf16), for PV B-operand staging
__global__ __launch_bounds__(256) void vtrans_kernel(const u16* __restrict__ qkv,
                                                     u16* __restrict__ Vt) {
  __shared__ u16 t[32][33];
  int bh = blockIdx.z, b = bh >> 4, h = bh & 15;
  const u16* Vg = qkv + (size_t)(32 + h) * NTOK * HS_ + (size_t)b * T_ * HS_;
  u16* Vp = Vt + (size_t)bh * HS_ * T_;
  int t0 = blockIdx.x * 32, c0 = blockIdx.y * 32;
  int tx = threadIdx.x & 31, ty = threadIdx.x >> 5;
#pragma unroll
  for (int i = 0; i < 32; i += 8)
    t[ty + i][tx] = Vg[(size_t)(t0 + ty + i) * HS_ + c0 + tx];
  __syncthreads();
#pragma unroll
  for (int i = 0; i < 32; i += 8)
    Vp[(size_t)(c0 + ty + i) * T_ + t0 + tx] = t[tx][ty + i];
}

// ---------------------------------------------------------------- gating
// exact fp32 gating so top-2 selection matches the reference
__global__ __launch_bounds__(256) void gating_kernel(
    const float* __restrict__ x, const float* __restrict__ Wg,
    int* __restrict__ sel, float* __restrict__ wgt) {
  int wave = threadIdx.x >> 6, lane = threadIdx.x & 63;
  int t = blockIdx.x * 4 + wave;
  int e = lane & 7, grp = lane >> 3;
  const float* xr = x + (size_t)t * D_;
  float acc = 0.f;
  for (int i = 0; i < 128; ++i) {
    int d = grp + i * 8;
    acc += xr[d] * Wg[d * 8 + e];
  }
  acc += __shfl_xor(acc, 8);
  acc += __shfl_xor(acc, 16);
  acc += __shfl_xor(acc, 32);
  float lg[8];
#pragma unroll
  for (int j = 0; j < 8; ++j) lg[j] = __shfl(acc, j);
  int s0 = 0; float v0 = lg[0];
#pragma unroll
  for (int j = 1; j < 8; ++j) if (lg[j] > v0) { v0 = lg[j]; s0 = j; }
  int s1 = -1; float v1 = -3.4e38f;
#pragma unroll
  for (int j = 0; j < 8; ++j) if (j != s0 && lg[j] > v1) { v1 = lg[j]; s1 = j; }
  if (lane == 0) {
    float dd = __expf(v1 - v0);
    float w0 = 1.f / (1.f + dd);
    sel[2 * t]     = s0; sel[2 * t + 1] = s1;
    wgt[2 * t]     = w0; wgt[2 * t + 1] = dd * w0;
  }
}

// meta[0..7]=counts, meta[8..15]=row offsets, meta[16..23]=m-block prefix, meta[24]=total m-blocks
__global__ __launch_bounds__(256) void offsets_kernel(const int* __restrict__ sel,
                                                      int* __restrict__ meta) {
  __shared__ int hist[E_];
  int tid = threadIdx.x;
  if (tid < E_) hist[tid] = 0;
  __syncthreads();
  for (int i = tid; i < NROW; i += 256) atomicAdd(&hist[sel[i]], 1);
  __syncthreads();
  if (tid == 0) {
    int s = 0, mb = 0;
    for (int e = 0; e < E_; ++e) {
      int c = hist[e];
      meta[e] = c; meta[8 + e] = s; meta[16 + e] = mb;
      s += c; mb += (c + 127) >> 7;
    }
    meta[24] = mb;
  }
}

// deterministic per-expert stable assignment via ballot scan
__global__ __launch_bounds__(256) void assign_kernel(
    const int* __restrict__ sel, const float* __restrict__ wgt,
    const int* __restrict__ meta, int* __restrict__ gidx,
    float* __restrict__ gw, int* __restrict__ rowmap) {
  int e = blockIdx.x, tid = threadIdx.x, lane = tid & 63, wv = tid >> 6;
  __shared__ int wsum[4];
  __shared__ int carry;
  if (tid == 0) carry = meta[8 + e];
  __syncthreads();
  for (int base = 0; base < NROW; base += 256) {
    int idx = base + tid;
    int f = (sel[idx] == e) ? 1 : 0;
    unsigned long long mask = __ballot(f);
    int pre = __popcll(mask & ((1ull << lane) - 1ull));
    if (lane == 0) wsum[wv] = __popcll(mask);
    __syncthreads();
    int woff = 0;
    for (int w = 0; w < wv; ++w) woff += wsum[w];
    int cb = carry;
    if (f) {
      int pos = cb + woff + pre;
      gidx[pos] = idx >> 1;
      gw[pos] = wgt[idx];
      rowmap[idx] = pos;
    }
    __syncthreads();
    if (tid == 0) carry = cb + wsum[0] + wsum[1] + wsum[2] + wsum[3];
    __syncthreads();
  }
}

// ---------------------------------------------------------------- GEMM (bf16 MFMA)
// C[m][n] = sum_k A[m][k] * Bt[n][k]; tile 128x128, BK=64, 4 waves as 2x2,
// each wave 64x64 = 4x4 mfma tiles. global_load_lds width-16 staging with
// XOR-swizzled LDS layout: LDS[row][p] holds logical 16B-chunk p^(row&7).
// Fragment read for row R, logical chunk c is at p=c^(R&7) -> full 32-bank
// spread (2 lanes/bank = free). Staging lane l fetches global chunk (l&7)^(l>>3).
// MODE 0: QKV  A=xbf[8192x1024], Bt=wqkvt[3072x1024], out planes qkv[48][8192][64]
// MODE 1: MoE1 A=xbf gathered via gidx, Bt=w1t[e], out H bf16 (+bias,relu)
// MODE 2: MoE2 A=Hbuf rows, Bt=w2t[e], out Y bf16 (+bias)
template <int MODE>
__global__ __launch_bounds__(256) void gemm_bt(
    const u16* __restrict__ A, const u16* __restrict__ Bt,
    u16* __restrict__ outB, const float* __restrict__ bias,
    const int* __restrict__ meta, const int* __restrict__ gidx, int K) {
  int n0 = blockIdx.y * 128;
  int n_e = 0, off = 0, m0, e = 0;
  const u16* Ap = A;
  const u16* Bp = Bt;
  if constexpr (MODE != 0) {
    int xb = blockIdx.x;
#pragma unroll
    for (int j = 1; j < 8; ++j) if (meta[16 + j] <= xb) e = j;
    n_e = meta[e];
    off = meta[8 + e];
    m0 = (xb - meta[16 + e]) * 128;
    if (m0 >= n_e) return;  // also catches xb >= meta[24]
    if constexpr (MODE == 1) {
      Bp = Bt + (size_t)e * DFF * 1024;
    } else {
      Ap = A + (size_t)off * DFF;
      Bp = Bt + (size_t)e * 1024 * DFF;
    }
  } else {
    m0 = blockIdx.x * 128;
  }

  __shared__ __align__(16) u16 As[128 * 64];
  __shared__ __align__(16) u16 Bs[128 * 64];
  int tid = threadIdx.x, lane = tid & 63, wave = tid >> 6;
  int wm = wave >> 1, wn = wave & 1, ml = lane & 15, quad = lane >> 4;
  int lrow = lane >> 3;                     // 0..7
  int gcol = ((lane & 7) ^ lrow) * 8;       // swizzled global column chunk

  // hoist per-lane global row pointers for the 4 staging slices
  const u16* arow[4];
  const u16* brow[4];
#pragma unroll
  for (int r = 0; r < 4; ++r) {
    int row = wave * 32 + r * 8;            // wave-uniform LDS base row
    int ra = m0 + row + lrow;
    if constexpr (MODE == 1) {
      int rr = ra < n_e ? ra : n_e - 1;
      arow[r] = Ap + (size_t)gidx[off + rr] * 1024 + gcol;
    } else if constexpr (MODE == 2) {
      int rr = ra < n_e ? ra : n_e - 1;
      arow[r] = Ap + (size_t)rr * DFF + gcol;
    } else {
      arow[r] = Ap + (size_t)ra * 1024 + gcol;
    }
    brow[r] = Bp + (size_t)(n0 + row + lrow) * K + gcol;
  }

  f4 acc[4][4];
#pragma unroll
  for (int i = 0; i < 4; ++i)
#pragma unroll
    for (int j = 0; j < 4; ++j) acc[i][j] = (f4){0.f, 0.f, 0.f, 0.f};

  int mlx = ml & 7;  // row&7 for fragment rows (bases are multiples of 8)
  for (int k0 = 0; k0 < K; k0 += 64) {
    __syncthreads();
#pragma unroll
    for (int r = 0; r < 4; ++r) {
      int row = wave * 32 + r * 8;
      async16(arow[r] + k0, &As[row * 64]);
      async16(brow[r] + k0, &Bs[row * 64]);
    }
    __syncthreads();  // drains vmcnt for global_load_lds
#pragma unroll
    for (int kk = 0; kk < 64; kk += 32) {
      int p = (((kk >> 3) + quad) ^ mlx) * 8;  // swizzled chunk offset (u16)
      bf8 af[4], bfr[4];
#pragma unroll
      for (int mi = 0; mi < 4; ++mi)
        af[mi] = *(const bf8*)&As[(wm * 64 + mi * 16 + ml) * 64 + p];
#pragma unroll
      for (int ni = 0; ni < 4; ++ni)
        bfr[ni] = *(const bf8*)&Bs[(wn * 64 + ni * 16 + ml) * 64 + p];
#pragma unroll
      for (int mi = 0; mi < 4; ++mi)
#pragma unroll
        for (int ni = 0; ni < 4; ++ni)
          acc[mi][ni] = mfma16(af[mi], bfr[ni], acc[mi][ni]);
    }
  }

#pragma unroll
  for (int mi = 0; mi < 4; ++mi)
#pragma unroll
    for (int ni = 0; ni < 4; ++ni)
#pragma unroll
      for (int rg = 0; rg < 4; ++rg) {
        int m = m0 + wm * 64 + mi * 16 + quad * 4 + rg;
        int n = n0 + wn * 64 + ni * 16 + ml;
        float v = acc[mi][ni][rg];
        if constexpr (MODE == 0) {
          int pl = n >> 6, col = n & 63;
          outB[(size_t)pl * NTOK * HS_ + (size_t)m * HS_ + col] = f2bf(v);
        } else if constexpr (MODE == 1) {
          if (m < n_e) {
            float hv = v + bias[e * DFF + n];
            outB[(size_t)(off + m) * DFF + n] = f2bf(fmaxf(hv, 0.f));
          }
        } else {
          if (m < n_e) {
            outB[(size_t)(off + m) * 1024 + n] = f2bf(v + bias[e * 1024 + n]);
          }
        }
      }
}

// ---------------------------------------------------------------- attention (bf16 MFMA flash)
__global__ __launch_bounds__(256) void attn_kernel(const u16* __restrict__ qkv,
                                                   const u16* __restrict__ Vt,
                                                   float* __restrict__ attn_out) {
  int qt = blockIdx.x, bh = blockIdx.y;
  int b = bh >> 4, h = bh & 15;
  int q0 = qt * 64;
  const u16* Qg = qkv + (size_t)h * NTOK * HS_ + (size_t)b * T_ * HS_;
  const u16* Kg = qkv + (size_t)(16 + h) * NTOK * HS_ + (size_t)b * T_ * HS_;
  const u16* Vp = Vt + (size_t)bh * HS_ * T_;
  __shared__ __align__(16) u16 Qs[64 * 72];
  __shared__ __align__(16) u16 Ks[64 * 72];
  __shared__ __align__(16) u16 Vs[64 * 72];   // Vs[c][j]
  __shared__ __align__(16) u16 Ps[64 * 72];   // wave w uses rows w*16..w*16+15
  int tid = threadIdx.x, lane = tid & 63, wave = tid >> 6;
  int ml = lane & 15, quad = lane >> 4;

  for (int i = tid; i < 512; i += 256) {
    int r = i >> 3, c = (i & 7) * 8;
    *(uint4*)&Qs[r * 72 + c] = *(const uint4*)(Qg + (size_t)(q0 + r) * HS_ + c);
  }

  f4 acc_o[4];
  float m_[4], l_[4];
#pragma unroll
  for (int i = 0; i < 4; ++i) {
    acc_o[i] = (f4){0.f, 0.f, 0.f, 0.f};
    m_[i] = -1e30f; l_[i] = 0.f;
  }

  for (int ck = 0; ck <= qt; ++ck) {
    int kv0 = ck * 64;
    __syncthreads();
    for (int i = tid; i < 512; i += 256) {
      int r = i >> 3, c = (i & 7) * 8;
      *(uint4*)&Ks[r * 72 + c] = *(const uint4*)(Kg + (size_t)(kv0 + r) * HS_ + c);
      *(uint4*)&Vs[r * 72 + c] = *(const uint4*)(Vp + (size_t)r * T_ + kv0 + c);
    }
    __syncthreads();

    // S = Q K^T (16x64 per wave)
    f4 sacc[4];
#pragma unroll
    for (int nt = 0; nt < 4; ++nt) sacc[nt] = (f4){0.f, 0.f, 0.f, 0.f};
#pragma unroll
    for (int kk = 0; kk < 64; kk += 32) {
      bf8 a = *(const bf8*)&Qs[(wave * 16 + ml) * 72 + kk + quad * 8];
#pragma unroll
      for (int nt = 0; nt < 4; ++nt) {
        bf8 bk = *(const bf8*)&Ks[(nt * 16 + ml) * 72 + kk + quad * 8];
        sacc[nt] = mfma16(a, bk, sacc[nt]);
      }
    }

    // online softmax; C-layout: row = quad*4+rg (strip-local), col = nt*16+ml
    bool dm = (kv0 == q0);  // only the diagonal chunk needs masking
    float pv[4][4], mx[4];
#pragma unroll
    for (int rg = 0; rg < 4; ++rg) {
      int gq = q0 + wave * 16 + quad * 4 + rg;
      float mm = -1e30f;
#pragma unroll
      for (int nt = 0; nt < 4; ++nt) {
        float s = sacc[nt][rg] * 0.03125f;  // D^-0.5
        if (dm && (kv0 + nt * 16 + ml) > gq) s = -1e30f;
        pv[nt][rg] = s;
        mm = fmaxf(mm, s);
      }
      mx[rg] = mm;
    }
#pragma unroll
    for (int off = 1; off < 16; off <<= 1)
#pragma unroll
      for (int rg = 0; rg < 4; ++rg) mx[rg] = fmaxf(mx[rg], __shfl_xor(mx[rg], off));

    float al[4], rs[4];
#pragma unroll
    for (int rg = 0; rg < 4; ++rg) {
      float mn = fmaxf(m_[rg], mx[rg]);
      al[rg] = __expf(m_[rg] - mn);
      m_[rg] = mn;
      float r = 0.f;
#pragma unroll
      for (int nt = 0; nt < 4; ++nt) {
        float ev = __expf(pv[nt][rg] - mn);
        pv[nt][rg] = ev;
        r += ev;
      }
      rs[rg] = r;
    }
#pragma unroll
    for (int off = 1; off < 16; off <<= 1)
#pragma unroll
      for (int rg = 0; rg < 4; ++rg) rs[rg] += __shfl_xor(rs[rg], off);

#pragma unroll
    for (int rg = 0; rg < 4; ++rg) {
      l_[rg] = al[rg] * l_[rg] + rs[rg];
#pragma unroll
      for (int nt = 0; nt < 4; ++nt) {
        acc_o[nt][rg] *= al[rg];
        Ps[(wave * 16 + quad * 4 + rg) * 72 + nt * 16 + ml] = f2bf(pv[nt][rg]);
      }
    }

    // PV: A = Ps strip (wave-local; in-wave LDS ordering suffices), B = Vs
#pragma unroll
    for (int kk = 0; kk < 64; kk += 32) {
      bf8 a = *(const bf8*)&Ps[(wave * 16 + ml) * 72 + kk + quad * 8];
#pragma unroll
      for (int ci = 0; ci < 4; ++ci) {
        bf8 bv = *(const bf8*)&Vs[(ci * 16 + ml) * 72 + kk + quad * 8];
        acc_o[ci] = mfma16(a, bv, acc_o[ci]);
      }
    }
  }

#pragma unroll
  for (int rg = 0; rg < 4; ++rg) {
    float inv = 1.f / l_[rg];
    int gq = q0 + wave * 16 + quad * 4 + rg;
    float* orow = attn_out + (size_t)(b * T_ + gq) * D_ + h * HS_;
#pragma unroll
    for (int ci = 0; ci < 4; ++ci) orow[ci * 16 + ml] = acc_o[ci][rg] * inv;
  }
}

// ---------------------------------------------------------------- final: out = x + LN(attn) + LN(moe)
__global__ __launch_bounds__(256) void final_kernel(
    const float* __restrict__ x, const float* __restrict__ attn,
    const u16* __restrict__ Y, const int* __restrict__ rowmap,
    const float* __restrict__ wgt,
    const float* __restrict__ g1, const float* __restrict__ be1,
    const float* __restrict__ g2, const float* __restrict__ be2,
    float* __restrict__ out) {
  int t = blockIdx.x, tid = threadIdx.x;
  int lane = tid & 63, wave = tid >> 6;
  float4 av = ((const float4*)(attn + (size_t)t * D_))[tid];
  int r0 = rowmap[2 * t], r1 = rowmap[2 * t + 1];
  float w0 = wgt[2 * t], w1 = wgt[2 * t + 1];
  ushort4 y0 = ((const ushort4*)(Y + (size_t)r0 * D_))[tid];
  ushort4 y1 = ((const ushort4*)(Y + (size_t)r1 * D_))[tid];
  float4 mv;
  mv.x = w0 * bf2f(y0.x) + w1 * bf2f(y1.x);
  mv.y = w0 * bf2f(y0.y) + w1 * bf2f(y1.y);
  mv.z = w0 * bf2f(y0.z) + w1 * bf2f(y1.z);
  mv.w = w0 * bf2f(y0.w) + w1 * bf2f(y1.w);

  float sa = av.x + av.y + av.z + av.w;
  float qa = av.x * av.x + av.y * av.y + av.z * av.z + av.w * av.w;
  float sm = mv.x + mv.y + mv.z + mv.w;
  float qm = mv.x * mv.x + mv.y * mv.y + mv.z * mv.z + mv.w * mv.w;
#pragma unroll
  for (int off = 1; off < 64; off <<= 1) {
    sa += __shfl_xor(sa, off);
    qa += __shfl_xor(qa, off);
    sm += __shfl_xor(sm, off);
    qm += __shfl_xor(qm, off);
  }
  __shared__ float red[4][4];
  if (lane == 0) { red[wave][0] = sa; red[wave][1] = qa; red[wave][2] = sm; red[wave][3] = qm; }
  __syncthreads();
  sa = red[0][0] + red[1][0] + red[2][0] + red[3][0];
  qa = red[0][1] + red[1][1] + red[2][1] + red[3][1];
  sm = red[0][2] + red[1][2] + red[2][2] + red[3][2];
  qm = red[0][3] + red[1][3] + red[2][3] + red[3][3];
  const float inv_d = 1.f / 1024.f;
  float mu1 = sa * inv_d, var1 = qa * inv_d - mu1 * mu1;
  float mu2 = sm * inv_d, var2 = qm * inv_d - mu2 * mu2;
  float rs1 = rsqrtf(var1 + 1e-5f), rs2 = rsqrtf(var2 + 1e-5f);

  float4 xv = ((const float4*)(x + (size_t)t * D_))[tid];
  float4 g1v = ((const float4*)g1)[tid], b1v = ((const float4*)be1)[tid];
  float4 g2v = ((const float4*)g2)[tid], b2v = ((const float4*)be2)[tid];
  float4 o;
  o.x = xv.x + (av.x - mu1) * rs1 * g1v.x + b1v.x + (mv.x - mu2) * rs2 * g2v.x + b2v.x;
  o.y = xv.y + (av.y - mu1) * rs1 * g1v.y + b1v.y + (mv.y - mu2) * rs2 * g2v.y + b2v.y;
  o.z = xv.z + (av.z - mu1) * rs1 * g1v.z + b1v.z + (mv.z - mu2) * rs2 * g2v.z + b2v.z;
  o.w = xv.w + (av.w - mu1) * rs1 * g1v.w + b1v.w + (mv.w - mu2) * rs2 * g2v.w + b2v.w;
  ((float4*)(out + (size_t)t * D_))[tid] = o;
}

// ---------------------------------------------------------------- launch
extern "C" void kernel_launch(void* const* d_in, const int* in_sizes, int n_in,
                              void* d_out, int out_size, void* d_ws, size_t ws_size,
                              hipStream_t stream) {
  const float* x   = (const float*)d_in[0];
  const float* Wq  = (const float*)d_in[1];
  const float* Wk  = (const float*)d_in[2];
  const float* Wv  = (const float*)d_in[3];
  const float* Wg  = (const float*)d_in[4];
  const float* W1  = (const float*)d_in[5];
  const float* b1  = (const float*)d_in[6];
  const float* W2  = (const float*)d_in[7];
  const float* b2  = (const float*)d_in[8];
  const float* g1  = (const float*)d_in[9];
  const float* be1 = (const float*)d_in[10];
  const float* g2  = (const float*)d_in[11];
  const float* be2 = (const float*)d_in[12];
  float* out = (float*)d_out;

  char* ws = (char*)d_ws;
  size_t off = 0;
  auto alloc = [&](size_t bytes) -> void* {
    void* p = ws + off;
    off = (off + bytes + 255) & ~(size_t)255;
    return p;
  };
  u16*   xbf    = (u16*)alloc((size_t)NTOK * D_ * 2);          // 16.8 MB
  u16*   wqkvt  = (u16*)alloc((size_t)48 * 64 * 1024 * 2);     // 6.3 MB  [3072][1024]
  u16*   w1t    = (u16*)alloc((size_t)E_ * DFF * 1024 * 2);    // 67 MB   [e][4096][1024]
  u16*   w2t    = (u16*)alloc((size_t)E_ * 1024 * DFF * 2);    // 67 MB   [e][1024][4096]
  u16*   qkv    = (u16*)alloc((size_t)48 * NTOK * HS_ * 2);    // 50 MB   [mat*16+h][8192][64]
  float* attn   = (float*)alloc((size_t)NTOK * D_ * 4);        // 33.5 MB
  u16*   Hbuf   = (u16*)alloc((size_t)NROW * DFF * 2);         // 134 MB
  u16*   Ybuf   = (u16*)alloc((size_t)NROW * 1024 * 2);        // 33.5 MB
  int*   meta   = (int*)alloc(256);
  int*   sel    = (int*)alloc(NROW * 4);
  float* wgt    = (float*)alloc(NROW * 4);
  int*   gidx   = (int*)alloc(NROW * 4);
  float* gw     = (float*)alloc(NROW * 4);
  int*   rowmap = (int*)alloc(NROW * 4);
  // Vt aliases Hbuf: consumed by attn_kernel before gemm_bt<1> writes Hbuf.
  u16*   Vt     = Hbuf;  // 16.7 MB [bh][64][1024]
  (void)ws_size; (void)in_sizes; (void)n_in; (void)out_size; (void)gw;

  // dtype converts / transposes (weights -> bf16, K-contiguous "B^T" layout)
  cvt_x_kernel<<<NTOK * D_ / 1024, 256, 0, stream>>>(x, xbf);
  transpose_cvt_kernel<<<dim3(32, 2, 16), 256, 0, stream>>>(Wq, wqkvt, 1024, 64, 65536, 65536);
  transpose_cvt_kernel<<<dim3(32, 2, 16), 256, 0, stream>>>(Wk, wqkvt + 16 * 65536, 1024, 64, 65536, 65536);
  transpose_cvt_kernel<<<dim3(32, 2, 16), 256, 0, stream>>>(Wv, wqkvt + 32 * 65536, 1024, 64, 65536, 65536);
  transpose_cvt_kernel<<<dim3(32, 128, 8), 256, 0, stream>>>(W1, w1t, 1024, 4096, (size_t)1024 * 4096, (size_t)1024 * 4096);
  transpose_cvt_kernel<<<dim3(128, 32, 8), 256, 0, stream>>>(W2, w2t, 4096, 1024, (size_t)4096 * 1024, (size_t)4096 * 1024);

  // routing
  gating_kernel<<<NTOK / 4, 256, 0, stream>>>(x, Wg, sel, wgt);
  offsets_kernel<<<1, 256, 0, stream>>>(sel, meta);
  assign_kernel<<<E_, 256, 0, stream>>>(sel, wgt, meta, gidx, gw, rowmap);

  // attention branch: QKV as one 8192x3072x1024 GEMM, then V transpose, then flash
  gemm_bt<0><<<dim3(64, 24), 256, 0, stream>>>(xbf, wqkvt, qkv, nullptr, nullptr, nullptr, 1024);
  vtrans_kernel<<<dim3(32, 2, 128), 256, 0, stream>>>(qkv, Vt);
  attn_kernel<<<dim3(16, 128), 256, 0, stream>>>(qkv, Vt, attn);

  // MoE branch: compacted m-block grid (worst case 136 = 128 + 8 partial tiles)
  gemm_bt<1><<<dim3(136, 32), 256, 0, stream>>>(xbf, w1t, Hbuf, b1, meta, gidx, 1024);
  gemm_bt<2><<<dim3(136, 8), 256, 0, stream>>>(Hbuf, w2t, Ybuf, b2, meta, gidx, 4096);

  // out = x + LN(attn) + LN(moe)
  final_kernel<<<NTOK, 256, 0, stream>>>(x, attn, Ybuf, rowmap, wgt, g1, be1, g2, be2, out);
}